// Round 5
// baseline (162.689 us; speedup 1.0000x reference)
//
#include <hip/hip_runtime.h>
#include <stdint.h>

// out[65536,64] = xa[65536,256] @ wa[256,64] + xb[65536,256] @ wb[256,64]
// Tall-skinny GEMM M=65536, N=64, K=512. L3-resident in the timed harness;
// prior rounds capped at ~2.85 TB/s effective delivery (latency/pattern).
// R4: coalesced block-cooperative reg-staged x (256B segments), bf16 LDS
// double-buffered panel (XOR-swizzled), raw s_barrier (no vmcnt drain),
// 1024 thr/block, 16 waves/CU, loads for chunk c+2 in flight across barrier.

#define WT_SHORTS  (512 * 64)       // 32768 bf16 = 64 KB
#define WT_BYTES   (WT_SHORTS * 2)
#define XPAN_BYTES (256 * 64 * 2)   // 32 KB per buffer

typedef __bf16 bf16x8 __attribute__((ext_vector_type(8)));
typedef __bf16 bf16x4 __attribute__((ext_vector_type(4)));
typedef float  f32x4  __attribute__((ext_vector_type(4)));

// Fragment-native weight layout (as R2):
//   wt[((sg*4 + cb)*64 + lane)*8 + j] = W[k][col],
//   k = sg*32 + (lane>>4)*8 + j  (0-255 -> wa, 256-511 -> wb),
//   col = (lane&15) + cb*16.
// Wave frag read = contiguous 1KB -> conflict-free.
__global__ void prep_wt_kernel(const float* __restrict__ wa,
                               const float* __restrict__ wb,
                               __bf16* __restrict__ wt) {
    int o2 = blockIdx.x * 256 + threadIdx.x;   // 0..16383
    #pragma unroll
    for (int h = 0; h < 2; ++h) {
        int o    = o2 * 2 + h;                 // 0..32767
        int j    = o & 7;
        int lane = (o >> 3) & 63;
        int cb   = (o >> 9) & 3;
        int s    = o >> 11;
        int k    = s * 32 + (lane >> 4) * 8 + j;
        int col  = (lane & 15) + cb * 16;
        float v  = (k < 256) ? wa[k * 64 + col] : wb[(k - 256) * 64 + col];
        wt[o] = (__bf16)v;
    }
}

template <bool USE_WS>
__global__ __launch_bounds__(1024, 4)
void agg_gemm_kernel(const float* __restrict__ xa,
                     const float* __restrict__ xb,
                     const float* __restrict__ wa,
                     const float* __restrict__ wb,
                     const __bf16* __restrict__ wt,
                     float* __restrict__ out) {
    __shared__ __align__(16) __bf16 wlds[WT_SHORTS];      // 64 KB weights
    __shared__ __align__(16) __bf16 xpan[2 * 256 * 64];   // 2 x 32 KB x panel

    const int t    = threadIdx.x;    // 0..1023
    const int lane = t & 63;
    const int wave = t >> 6;         // 0..15

    // ---- weights -> LDS (completes at prologue barrier) ----
    if (USE_WS) {
        const f32x4* g = (const f32x4*)wt;
        f32x4*       l = (f32x4*)&wlds[0];
        #pragma unroll
        for (int it = 0; it < 4; ++it)
            l[it * 1024 + t] = g[it * 1024 + t];
    } else {
        for (int i = 0; i < 32; ++i) {
            int o    = t * 32 + i;
            int j    = o & 7;
            int ln   = (o >> 3) & 63;
            int cb   = (o >> 9) & 3;
            int s    = o >> 11;
            int k    = s * 32 + (ln >> 4) * 8 + j;
            int col  = (ln & 15) + cb * 16;
            wlds[o] = (__bf16)((k < 256) ? wa[k * 64 + col]
                                         : wb[(k - 256) * 64 + col]);
        }
    }

    const int row0 = blockIdx.x * 256;   // block's first output row

    // ---- staging: chunk c = 64 floats of K; flat = j*1024 + t ----
    // row = flat>>4 (0..255), p = flat&15 -> floats [p*4, p*4+4) of the chunk.
    // Per wave-load: 4 rows x 256B contiguous segments (coalesced).
    const int srow = t >> 4;   // + j*64
    const int sp   = t & 15;

    auto issue = [&](int c, f32x4 (&r)[4]) {
        const float* src = ((c < 4) ? xa : xb)
                         + (size_t)row0 * 256 + (c & 3) * 64 + sp * 4;
        #pragma unroll
        for (int j = 0; j < 4; ++j)
            r[j] = *(const f32x4*)(src + (size_t)(j * 64 + srow) * 256);
    };

    // LDS panel: [row][kf] bf16, row stride 128B, byte ^= (row&7)<<4.
    auto lds_write = [&](int c, const f32x4 (&r)[4]) {
        char* buf = (char*)xpan + (c & 1) * XPAN_BYTES;
        #pragma unroll
        for (int j = 0; j < 4; ++j) {
            int row = j * 64 + srow;
            bf16x4 v;
            v[0] = (__bf16)r[j][0]; v[1] = (__bf16)r[j][1];
            v[2] = (__bf16)r[j][2]; v[3] = (__bf16)r[j][3];
            *(bf16x4*)(buf + ((row * 128 + sp * 8) ^ ((row & 7) << 4))) = v;
        }
    };

    // ---- MFMA fragment addressing ----
    const int r_     = lane & 15;          // D-col / A-row-in-frag
    const int kg     = lane >> 4;          // 0..3
    const int prow   = wave * 16 + r_;     // panel row
    const int xbyte0 = prow * 128 + kg * 16;
    const int xsw    = (r_ & 7) << 4;

    f32x4 acc0 = {0.f, 0.f, 0.f, 0.f};
    f32x4 acc1 = acc0, acc2 = acc0, acc3 = acc0;

    auto mstep = [&](int c) {
        const char* buf = (const char*)xpan + (c & 1) * XPAN_BYTES;
        #pragma unroll
        for (int s = 0; s < 2; ++s) {
            bf16x8 af = *(const bf16x8*)(buf + ((xbyte0 + s * 64) ^ xsw));
            const int sg = c * 2 + s;
            const __bf16* w0p = &wlds[(sg * 4) * 512 + lane * 8];
            bf16x8 w0 = *(const bf16x8*)(w0p);
            bf16x8 w1 = *(const bf16x8*)(w0p + 512);
            bf16x8 w2 = *(const bf16x8*)(w0p + 1024);
            bf16x8 w3 = *(const bf16x8*)(w0p + 1536);
            acc0 = __builtin_amdgcn_mfma_f32_16x16x32_bf16(af, w0, acc0, 0, 0, 0);
            acc1 = __builtin_amdgcn_mfma_f32_16x16x32_bf16(af, w1, acc1, 0, 0, 0);
            acc2 = __builtin_amdgcn_mfma_f32_16x16x32_bf16(af, w2, acc2, 0, 0, 0);
            acc3 = __builtin_amdgcn_mfma_f32_16x16x32_bf16(af, w3, acc3, 0, 0, 0);
        }
    };

    // ---- pipeline: 8 chunks (xa k0..3, xb k0..3), dbuf, 1 barrier/chunk ----
    f32x4 rA[4], rB[4];
    issue(0, rA);
    issue(1, rB);
    lds_write(0, rA);
    asm volatile("s_waitcnt lgkmcnt(0)" ::: "memory");
    __builtin_amdgcn_s_barrier();        // buf0 + weights ready (vmcnt NOT drained)

    #pragma unroll
    for (int c = 0; c < 8; ++c) {
        if (c < 6) {
            if (c & 1) issue(c + 2, rB); else issue(c + 2, rA);
            __builtin_amdgcn_sched_barrier(0);   // pin load issue before barrier
        }
        if (c < 7) {
            if (c & 1) lds_write(c + 1, rA); else lds_write(c + 1, rB);
        }
        mstep(c);
        asm volatile("s_waitcnt lgkmcnt(0)" ::: "memory");
        __builtin_amdgcn_s_barrier();
    }

    // ---- epilogue: D col = r_, D row = kg*4 + reg ----
    float* po = out + (size_t)(row0 + wave * 16 + kg * 4) * 64 + r_;
    #pragma unroll
    for (int r = 0; r < 4; ++r) {
        po[r * 64 +  0] = acc0[r];
        po[r * 64 + 16] = acc1[r];
        po[r * 64 + 32] = acc2[r];
        po[r * 64 + 48] = acc3[r];
    }
}

extern "C" void kernel_launch(void* const* d_in, const int* in_sizes, int n_in,
                              void* d_out, int out_size, void* d_ws, size_t ws_size,
                              hipStream_t stream) {
    const float* xa = (const float*)d_in[0];
    const float* xb = (const float*)d_in[1];
    const float* wa = (const float*)d_in[2];
    const float* wb = (const float*)d_in[3];
    float* out = (float*)d_out;

    if (ws_size >= (size_t)WT_BYTES) {
        __bf16* wt = (__bf16*)d_ws;
        prep_wt_kernel<<<64, 256, 0, stream>>>(wa, wb, wt);
        agg_gemm_kernel<true><<<256, 1024, 0, stream>>>(xa, xb, wa, wb, wt, out);
    } else {
        agg_gemm_kernel<false><<<256, 1024, 0, stream>>>(xa, xb, wa, wb, nullptr, out);
    }
}